// Round 2
// baseline (436.089 us; speedup 1.0000x reference)
//
#include <hip/hip_runtime.h>

#define BIN_NUM 20
#define FEAT 64
#define HALF 10
// H*W = 256*256 = 65536 elements per (batch, channel) plane.
// In float4 units: 65536/4 = 16384 = 2^14 per plane -> channel = (i4 >> 14) & 63.

__global__ __launch_bounds__(256) void mtlu_kernel(
    const float* __restrict__ x,
    const float* __restrict__ mtlu_y,
    const float* __restrict__ mtlu_y_,
    float* __restrict__ out,
    int n4)
{
    __shared__ float s_w[FEAT * BIN_NUM];
    __shared__ float s_b[FEAT * BIN_NUM];

    // Build per-channel slope/intercept tables once per block (1280 entries each).
    for (int t = threadIdx.x; t < FEAT * BIN_NUM; t += blockDim.x) {
        int bin = t % BIN_NUM;                       // 0..19
        float y  = mtlu_y[t];
        float y_ = mtlu_y_[t];
        float d  = y - y_;
        float idxf = (float)(bin - (HALF - 1));      // -9..10, matches reference `index`
        s_w[t] = d / 0.1f;                           // (y - y_) / BinWidth
        s_b[t] = y - d * idxf;                       // y - (y - y_)*index
    }
    __syncthreads();

    const int stride = gridDim.x * blockDim.x;
    for (int i = blockIdx.x * blockDim.x + threadIdx.x; i < n4; i += stride) {
        float4 v = reinterpret_cast<const float4*>(x)[i];
        int c = (i >> 14) & 63;                      // channel for this float4
        const float* wrow = &s_w[c * BIN_NUM];
        const float* brow = &s_b[c * BIN_NUM];
        float4 o;

        {
            float xv = v.x;
            int bin = (int)floorf(xv / 0.1f) + HALF; // IEEE div to match jnp exactly
            bin = bin < 0 ? 0 : (bin > BIN_NUM - 1 ? BIN_NUM - 1 : bin);
            o.x = wrow[bin] * xv + brow[bin];
        }
        {
            float xv = v.y;
            int bin = (int)floorf(xv / 0.1f) + HALF;
            bin = bin < 0 ? 0 : (bin > BIN_NUM - 1 ? BIN_NUM - 1 : bin);
            o.y = wrow[bin] * xv + brow[bin];
        }
        {
            float xv = v.z;
            int bin = (int)floorf(xv / 0.1f) + HALF;
            bin = bin < 0 ? 0 : (bin > BIN_NUM - 1 ? BIN_NUM - 1 : bin);
            o.z = wrow[bin] * xv + brow[bin];
        }
        {
            float xv = v.w;
            int bin = (int)floorf(xv / 0.1f) + HALF;
            bin = bin < 0 ? 0 : (bin > BIN_NUM - 1 ? BIN_NUM - 1 : bin);
            o.w = wrow[bin] * xv + brow[bin];
        }

        reinterpret_cast<float4*>(out)[i] = o;
    }
}

extern "C" void kernel_launch(void* const* d_in, const int* in_sizes, int n_in,
                              void* d_out, int out_size, void* d_ws, size_t ws_size,
                              hipStream_t stream) {
    const float* x       = (const float*)d_in[0];   // [16, 64, 256, 256]
    const float* mtlu_y  = (const float*)d_in[1];   // [64, 20]
    const float* mtlu_y_ = (const float*)d_in[2];   // [64, 20]
    float* out = (float*)d_out;

    int n  = in_sizes[0];        // 67,108,864
    int n4 = n / 4;              // 16,777,216 float4s

    // 2048 blocks x 256 threads = 8192 waves = 32 waves/CU across 256 CUs.
    mtlu_kernel<<<dim3(2048), dim3(256), 0, stream>>>(x, mtlu_y, mtlu_y_, out, n4);
}